// Round 4
// baseline (178.959 us; speedup 1.0000x reference)
//
#include <hip/hip_runtime.h>

// B=8, N=256, D=128, 2D=256.
// out = tour [8,256] (arange) ++ improvement_matrix [8,256,256].

typedef __attribute__((ext_vector_type(8))) short short8;
typedef __attribute__((ext_vector_type(4))) float floatx4;

static __device__ __forceinline__ unsigned short f2bf(float f) {
  unsigned int x = __float_as_uint(f);
  x += 0x7fff + ((x >> 16) & 1);   // RNE fp32 -> bf16
  return (unsigned short)(x >> 16);
}

static __device__ __forceinline__ float fast_tanh(float x) {
  float e = __expf(2.0f * fabsf(x));                       // e^{2|x|}
  float t = 1.0f - 2.0f * __builtin_amdgcn_rcpf(e + 1.0f); // in [0,1)
  return copysignf(t, x);
}

// ---- k_proj: blocks 0..511 proj GEMM; 512..527 W2->bf16T; 528 tour out ----
// Pi' = x@W1a + x_next@W1b + b1 ; Pj = x@W1c + x_next@W1d  (both stored bf16)
__global__ __launch_bounds__(256) void k_proj(
    const float* __restrict__ x, const float* __restrict__ W1,
    const float* __restrict__ b1, const float* __restrict__ W2,
    float* __restrict__ out, unsigned short* __restrict__ PiB,
    unsigned short* __restrict__ PjB, unsigned short* __restrict__ W2T) {
  const int blk = blockIdx.x;
  const int tid = threadIdx.x;
  if (blk >= 512) {
    if (blk == 528) {
#pragma unroll
      for (int it = 0; it < 8; ++it) {
        int e = it * 256 + tid;
        out[e] = (float)(e & 255);          // improved_tour rows = arange
      }
    } else {
      int base = (blk - 512) * 2048;        // 16 blocks x 2048 = 32768 W2 elems
#pragma unroll
      for (int it = 0; it < 8; ++it) {
        int e = base + it * 256 + tid;      // W2 is [256 k][128 n]
        int k = e >> 7, n = e & 127;
        W2T[n * 256 + k] = f2bf(W2[e]);     // W2T[n][k]
      }
    }
    return;
  }
  __shared__ float xs[5][128];              // rows n0..n0+4 (wrap mod 256)
  const int b = blk >> 6;
  const int n0 = (blk & 63) * 4;
  for (int it = 0; it < 3; ++it) {
    int e = it * 256 + tid;
    if (e < 640) {
      int r = e >> 7, d = e & 127;
      xs[r][d] = x[(b * 256 + ((n0 + r) & 255)) * 128 + d];
    }
  }
  __syncthreads();
  const int c = tid;                        // output channel 0..255
  float api[4] = {0, 0, 0, 0}, apj[4] = {0, 0, 0, 0};
#pragma unroll 4
  for (int d = 0; d < 128; ++d) {
    float wa = W1[d * 256 + c];
    float wb = W1[(128 + d) * 256 + c];
    float wc = W1[(256 + d) * 256 + c];
    float wd = W1[(384 + d) * 256 + c];
    float xv[5];
#pragma unroll
    for (int r = 0; r < 5; ++r) xv[r] = xs[r][d];
#pragma unroll
    for (int r = 0; r < 4; ++r) {
      api[r] += xv[r] * wa + xv[r + 1] * wb;
      apj[r] += xv[r] * wc + xv[r + 1] * wd;
    }
  }
  const float bv = b1[c];
#pragma unroll
  for (int r = 0; r < 4; ++r) {
    int n = n0 + r;
    PiB[(b * 256 + n) * 256 + c] = f2bf(api[r] + bv);  // b1 folded into Pi'
    PjB[(b * 256 + n) * 256 + c] = f2bf(apj[r]);
  }
}

// ---- k_main: 512 thr = 8 waves x 32 j (256 j total); block persists over
// 2 i-values. acc = 64 regs/wave; __launch_bounds__(512,4) caps 128 VGPR ->
// 2 blocks/CU = 16 waves/CU so sibling waves fill MFMA/VALU issue gaps.
// W2 (full K=256, 64KB) staged in LDS once; ONE barrier total.
__global__ __launch_bounds__(512, 4) void k_main(
    const unsigned short* __restrict__ PiB, const unsigned short* __restrict__ PjB,
    const unsigned short* __restrict__ W2T, const float* __restrict__ b2,
    const float* __restrict__ W3, const float* __restrict__ b3,
    float* __restrict__ outm) {
  const int bid = blockIdx.x;           // 1024 = 8 b * 128 igroups
  const int b = bid >> 7;
  const int ig = bid & 127;
  const int tid = threadIdx.x;
  const int wr = tid >> 6;              // wave 0..7 -> j-range [wr*32, wr*32+32)
  const int lane = tid & 63, quad = lane >> 4, l15 = lane & 15;

  __shared__ unsigned short W2s[128][256];   // [n][k'] 16B-block XOR swizzle

  // stage W2 (64KB): row n = it*16 + tid>>5, k-block v = tid&31; swizzle col
  {
    const int n15 = tid >> 5;                // n & 15 (it-invariant)
    const int v = tid & 31;
    const int col = ((v & 16) | ((v ^ n15) & 15)) << 3;
    char* dst = (char*)&W2s[n15][col];
    const unsigned short* src = W2T + tid * 8;
#pragma unroll
    for (int it = 0; it < 8; ++it)
      *(uint4*)(dst + it * 8192) = *(const uint4*)(src + it * 4096);
  }
  __syncthreads();

  // epilogue constants (per lane, reused across both i)
  const float b3v = b3[0];
  float w3v[8], b2v[8];
#pragma unroll
  for (int nt = 0; nt < 8; ++nt) {
    w3v[nt] = W3[nt * 16 + l15];
    b2v[nt] = b2[nt * 16 + l15];
  }

  // LDS B-frag byte address: n*512 + ((bk&16)|((bk^n)&15))<<4,
  // n = nt*16+l15, bk = ks*4+quad  ->  (l15*512 + (quad^l15)<<4) ^ (ks<<6)
  // + nt*8192 as immediate offset.
  const char* W2base = (const char*)&W2s[0][0];
  const int base_sw = l15 * 512 + ((quad ^ l15) << 4);

  const unsigned short* Pjb = PjB + ((b << 8) + wr * 32 + l15) * 256 + quad * 8;

  for (int ii = 0; ii < 2; ++ii) {
    const int i = ig * 2 + ii;
    float* orow = outm + ((b << 8) + i) * 256 + wr * 32;
    if (i > wr * 32 + 29) {              // whole wave's 32 j invalid
      if (lane < 32) orow[lane] = 0.f;
      continue;
    }

    floatx4 acc[2][8];
#pragma unroll
    for (int mt = 0; mt < 2; ++mt)
#pragma unroll
      for (int nt = 0; nt < 8; ++nt) acc[mt][nt] = (floatx4)0.f;

    const unsigned short* PiRow = PiB + ((b << 8) + i) * 256 + quad * 8;

    // 2-deep register pipeline over ks (fully unrolled)
    uint4 pj0[2], pj1[2], pi0, pi1;
    pi0 = *(const uint4*)(PiRow);
    pj0[0] = *(const uint4*)(Pjb);
    pj0[1] = *(const uint4*)(Pjb + 4096);      // mt=1: +16 rows

#pragma unroll
    for (int ks = 0; ks < 8; ++ks) {
      const uint4* pjc = (ks & 1) ? pj1 : pj0;
      uint4* pjn = (ks & 1) ? pj0 : pj1;
      const uint4 picur = (ks & 1) ? pi1 : pi0;
      if (ks < 7) {                    // prefetch ks+1
        if (ks & 1) pi0 = *(const uint4*)(PiRow + (ks + 1) * 32);
        else        pi1 = *(const uint4*)(PiRow + (ks + 1) * 32);
        pjn[0] = *(const uint4*)(Pjb + (ks + 1) * 32);
        pjn[1] = *(const uint4*)(Pjb + 4096 + (ks + 1) * 32);
      }
      // unpack Pi fragment (8 elems), shared across mt
      float pif[8];
#pragma unroll
      for (int p = 0; p < 4; ++p) {
        unsigned w = ((const unsigned*)&picur)[p];
        pif[2 * p]     = __uint_as_float(w << 16);
        pif[2 * p + 1] = __uint_as_float(w & 0xffff0000u);
      }
      // build A-frags: relu(Pi + Pj[j]) -> packed bf16 (truncate via perm)
      short8 af[2];
#pragma unroll
      for (int mt = 0; mt < 2; ++mt) {
        union { unsigned u[4]; short8 s; } cvt;
#pragma unroll
        for (int p = 0; p < 4; ++p) {
          unsigned w = ((const unsigned*)&pjc[mt])[p];
          float lo = fmaxf(pif[2 * p]     + __uint_as_float(w << 16), 0.f);
          float hi = fmaxf(pif[2 * p + 1] + __uint_as_float(w & 0xffff0000u), 0.f);
          cvt.u[p] = __builtin_amdgcn_perm(__float_as_uint(hi), __float_as_uint(lo),
                                           0x07060302u);  // {hi16(hi),hi16(lo)}
        }
        af[mt] = cvt.s;
      }
      // MFMA burst: 8 n-tiles x 2 m-tiles
      const char* baddr = W2base + (base_sw ^ (ks << 6));
#pragma unroll
      for (int nt = 0; nt < 8; ++nt) {
        short8 bfr = *(const short8*)(baddr + nt * 8192);
        acc[0][nt] = __builtin_amdgcn_mfma_f32_16x16x32_bf16(af[0], bfr, acc[0][nt], 0, 0, 0);
        acc[1][nt] = __builtin_amdgcn_mfma_f32_16x16x32_bf16(af[1], bfr, acc[1][nt], 0, 0, 0);
      }
    }

    // epilogue: score[j] = tanh(sum_n W3[n]*relu(C[j,n]+b2[n]) + b3), masked
#pragma unroll
    for (int mt = 0; mt < 2; ++mt) {
      float p0 = 0, p1 = 0, p2 = 0, p3 = 0;
#pragma unroll
      for (int nt = 0; nt < 8; ++nt) {
        floatx4 a = acc[mt][nt];
        p0 += fmaxf(a[0] + b2v[nt], 0.f) * w3v[nt];
        p1 += fmaxf(a[1] + b2v[nt], 0.f) * w3v[nt];
        p2 += fmaxf(a[2] + b2v[nt], 0.f) * w3v[nt];
        p3 += fmaxf(a[3] + b2v[nt], 0.f) * w3v[nt];
      }
#pragma unroll
      for (int m = 8; m >= 1; m >>= 1) {   // reduce over the 16 n-cols per quad
        p0 += __shfl_xor(p0, m, 16);
        p1 += __shfl_xor(p1, m, 16);
        p2 += __shfl_xor(p2, m, 16);
        p3 += __shfl_xor(p3, m, 16);
      }
      if (l15 == 0) {
        const int jl = wr * 32 + mt * 16 + quad * 4;   // global j of reg 0
        float ps[4] = {p0, p1, p2, p3};
#pragma unroll
        for (int r = 0; r < 4; ++r) {
          int j = jl + r;
          float s = fast_tanh(ps[r] + b3v);
          bool valid = (j >= i + 2) && (j - i != 255);
          orow[mt * 16 + quad * 4 + r] = valid ? s : 0.f;
        }
      }
    }
  }
}

extern "C" void kernel_launch(void* const* d_in, const int* in_sizes, int n_in,
                              void* d_out, int out_size, void* d_ws, size_t ws_size,
                              hipStream_t stream) {
  const float* x  = (const float*)d_in[0];   // [8,256,128]
  const float* W1 = (const float*)d_in[1];   // [512,256]
  const float* b1 = (const float*)d_in[2];   // [256]
  const float* W2 = (const float*)d_in[3];   // [256,128]
  const float* b2 = (const float*)d_in[4];   // [128]
  const float* W3 = (const float*)d_in[5];   // [128]
  const float* b3 = (const float*)d_in[6];   // [1]
  float* out = (float*)d_out;

  // workspace: PiB bf16 (1MB) | PjB bf16 (1MB) | W2T bf16 (64KB)
  unsigned short* PiB = (unsigned short*)d_ws;
  unsigned short* PjB = PiB + 8 * 256 * 256;
  unsigned short* W2T = PjB + 8 * 256 * 256;

  k_proj<<<529, 256, 0, stream>>>(x, W1, b1, W2, out, PiB, PjB, W2T);
  k_main<<<1024, 512, 0, stream>>>(PiB, PjB, W2T, b2, W3, b3, out + 2048);
}

// Round 5
// 127.347 us; speedup vs baseline: 1.4053x; 1.4053x over previous
//
#include <hip/hip_runtime.h>

// B=8, N=256, D=128, 2D=256.
// out = tour [8,256] (arange) ++ improvement_matrix [8,256,256].

typedef __attribute__((ext_vector_type(8))) short short8;
typedef __attribute__((ext_vector_type(4))) float floatx4;

static __device__ __forceinline__ unsigned short f2bf(float f) {
  unsigned int x = __float_as_uint(f);
  x += 0x7fff + ((x >> 16) & 1);   // RNE fp32 -> bf16
  return (unsigned short)(x >> 16);
}

static __device__ __forceinline__ float fast_tanh(float x) {
  float e = __expf(2.0f * fabsf(x));                       // e^{2|x|}
  float t = 1.0f - 2.0f * __builtin_amdgcn_rcpf(e + 1.0f); // in [0,1)
  return copysignf(t, x);
}

// ---- k_proj: blocks 0..511 proj GEMM; 512..527 W2->bf16T; 528 tour out ----
// Pi' = x@W1a + x_next@W1b + b1 ; Pj = x@W1c + x_next@W1d  (both stored bf16)
__global__ __launch_bounds__(256) void k_proj(
    const float* __restrict__ x, const float* __restrict__ W1,
    const float* __restrict__ b1, const float* __restrict__ W2,
    float* __restrict__ out, unsigned short* __restrict__ PiB,
    unsigned short* __restrict__ PjB, unsigned short* __restrict__ W2T) {
  const int blk = blockIdx.x;
  const int tid = threadIdx.x;
  if (blk >= 512) {
    if (blk == 528) {
#pragma unroll
      for (int it = 0; it < 8; ++it) {
        int e = it * 256 + tid;
        out[e] = (float)(e & 255);          // improved_tour rows = arange
      }
    } else {
      int base = (blk - 512) * 2048;        // 16 blocks x 2048 = 32768 W2 elems
#pragma unroll
      for (int it = 0; it < 8; ++it) {
        int e = base + it * 256 + tid;      // W2 is [256 k][128 n]
        int k = e >> 7, n = e & 127;
        W2T[n * 256 + k] = f2bf(W2[e]);     // W2T[n][k]
      }
    }
    return;
  }
  __shared__ float xs[5][128];              // rows n0..n0+4 (wrap mod 256)
  const int b = blk >> 6;
  const int n0 = (blk & 63) * 4;
  for (int it = 0; it < 3; ++it) {
    int e = it * 256 + tid;
    if (e < 640) {
      int r = e >> 7, d = e & 127;
      xs[r][d] = x[(b * 256 + ((n0 + r) & 255)) * 128 + d];
    }
  }
  __syncthreads();
  const int c = tid;                        // output channel 0..255
  float api[4] = {0, 0, 0, 0}, apj[4] = {0, 0, 0, 0};
#pragma unroll 4
  for (int d = 0; d < 128; ++d) {
    float wa = W1[d * 256 + c];
    float wb = W1[(128 + d) * 256 + c];
    float wc = W1[(256 + d) * 256 + c];
    float wd = W1[(384 + d) * 256 + c];
    float xv[5];
#pragma unroll
    for (int r = 0; r < 5; ++r) xv[r] = xs[r][d];
#pragma unroll
    for (int r = 0; r < 4; ++r) {
      api[r] += xv[r] * wa + xv[r + 1] * wb;
      apj[r] += xv[r] * wc + xv[r + 1] * wd;
    }
  }
  const float bv = b1[c];
#pragma unroll
  for (int r = 0; r < 4; ++r) {
    int n = n0 + r;
    PiB[(b * 256 + n) * 256 + c] = f2bf(api[r] + bv);  // b1 folded into Pi'
    PjB[(b * 256 + n) * 256 + c] = f2bf(apj[r]);
  }
}

// ---- k_main: 1024 thr = 16 waves x 16 j (all 256 j), one block per (b,i).
// acc = 32 AGPR/wave + ~60-90 arch VGPR fits the 128-reg/wave cap that
// __launch_bounds__(1024,4) imposes -> 4 waves/SIMD co-resident (vs 2 in R3,
// vs R4's spill disaster). W2 (full K=256, 64KB) staged once; ONE barrier.
__global__ __launch_bounds__(1024, 4) void k_main(
    const unsigned short* __restrict__ PiB, const unsigned short* __restrict__ PjB,
    const unsigned short* __restrict__ W2T, const float* __restrict__ b2,
    const float* __restrict__ W3, const float* __restrict__ b3,
    float* __restrict__ outm) {
  const int bid = blockIdx.x;           // 2048 = 8 b * 256 i
  const int i = bid & 255;
  const int b = bid >> 8;
  const int tid = threadIdx.x;
  const int wr = tid >> 6;              // wave 0..15 -> j-range [wr*16, wr*16+16)
  const int lane = tid & 63, quad = lane >> 4, l15 = lane & 15;

  __shared__ unsigned short W2s[128][256];   // [n][k'] 16B-block XOR swizzle

  // stage W2 (64KB): 4096 16B chunks, 4 per thread
  {
    const int rown = tid >> 5;               // 0..31 (n base; n&15 = rown&15)
    const int v = tid & 31;                  // k-block 0..31
    const int col = ((v & 16) | ((v ^ (rown & 15)) & 15)) << 3;
    char* dst = (char*)&W2s[rown][col];
    const unsigned short* src = W2T + rown * 256 + v * 8;
#pragma unroll
    for (int it = 0; it < 4; ++it)
      *(uint4*)(dst + it * 16384) = *(const uint4*)(src + it * 8192);
  }
  __syncthreads();

  float* orow = outm + ((b << 8) + i) * 256 + wr * 16;
  if (i > wr * 16 + 13) {              // whole wave's 16 j invalid
    if (lane < 16) orow[lane] = 0.f;
    return;
  }

  floatx4 acc[8];
#pragma unroll
  for (int nt = 0; nt < 8; ++nt) acc[nt] = (floatx4)0.f;

  const unsigned short* PiRow = PiB + ((b << 8) + i) * 256 + quad * 8;
  const unsigned short* Pjb = PjB + ((b << 8) + wr * 16 + l15) * 256 + quad * 8;

  // LDS B-frag byte address: (l15*512 + (quad^l15)<<4) ^ (ks<<6) + nt*8192
  const char* W2base = (const char*)&W2s[0][0];
  const int base_sw = l15 * 512 + ((quad ^ l15) << 4);

#pragma unroll
  for (int ks = 0; ks < 8; ++ks) {
    const uint4 pi4 = *(const uint4*)(PiRow + ks * 32);
    const uint4 pj4 = *(const uint4*)(Pjb + ks * 32);
    // build A-frag: relu(Pi + Pj[j]) -> packed bf16 (truncate via perm)
    union { unsigned u[4]; short8 s; } cvt;
#pragma unroll
    for (int p = 0; p < 4; ++p) {
      unsigned wi = ((const unsigned*)&pi4)[p];
      unsigned wj = ((const unsigned*)&pj4)[p];
      float lo = fmaxf(__uint_as_float(wi << 16) + __uint_as_float(wj << 16), 0.f);
      float hi = fmaxf(__uint_as_float(wi & 0xffff0000u) +
                       __uint_as_float(wj & 0xffff0000u), 0.f);
      cvt.u[p] = __builtin_amdgcn_perm(__float_as_uint(hi), __float_as_uint(lo),
                                       0x07060302u);  // {hi16(hi),hi16(lo)}
    }
    const short8 af = cvt.s;
    const char* baddr = W2base + (base_sw ^ (ks << 6));
#pragma unroll
    for (int nt = 0; nt < 8; ++nt) {
      short8 bfr = *(const short8*)(baddr + nt * 8192);
      acc[nt] = __builtin_amdgcn_mfma_f32_16x16x32_bf16(af, bfr, acc[nt], 0, 0, 0);
    }
  }

  // epilogue: score[j] = tanh(sum_n W3[n]*relu(C[j,n]+b2[n]) + b3), masked
  const float b3v = b3[0];
  float p0 = 0, p1 = 0, p2 = 0, p3 = 0;
#pragma unroll
  for (int nt = 0; nt < 8; ++nt) {
    float w3v = W3[nt * 16 + l15];
    float b2v = b2[nt * 16 + l15];
    floatx4 a = acc[nt];
    p0 += fmaxf(a[0] + b2v, 0.f) * w3v;
    p1 += fmaxf(a[1] + b2v, 0.f) * w3v;
    p2 += fmaxf(a[2] + b2v, 0.f) * w3v;
    p3 += fmaxf(a[3] + b2v, 0.f) * w3v;
  }
#pragma unroll
  for (int m = 8; m >= 1; m >>= 1) {   // reduce over the 16 n-cols per quad
    p0 += __shfl_xor(p0, m, 16);
    p1 += __shfl_xor(p1, m, 16);
    p2 += __shfl_xor(p2, m, 16);
    p3 += __shfl_xor(p3, m, 16);
  }
  if (l15 == 0) {
    const int jl = wr * 16 + quad * 4;     // global j of reg 0
    float ps[4] = {p0, p1, p2, p3};
#pragma unroll
    for (int r = 0; r < 4; ++r) {
      int j = jl + r;
      float s = fast_tanh(ps[r] + b3v);
      bool valid = (j >= i + 2) && (j - i != 255);
      orow[quad * 4 + r] = valid ? s : 0.f;
    }
  }
}

extern "C" void kernel_launch(void* const* d_in, const int* in_sizes, int n_in,
                              void* d_out, int out_size, void* d_ws, size_t ws_size,
                              hipStream_t stream) {
  const float* x  = (const float*)d_in[0];   // [8,256,128]
  const float* W1 = (const float*)d_in[1];   // [512,256]
  const float* b1 = (const float*)d_in[2];   // [256]
  const float* W2 = (const float*)d_in[3];   // [256,128]
  const float* b2 = (const float*)d_in[4];   // [128]
  const float* W3 = (const float*)d_in[5];   // [128]
  const float* b3 = (const float*)d_in[6];   // [1]
  float* out = (float*)d_out;

  // workspace: PiB bf16 (1MB) | PjB bf16 (1MB) | W2T bf16 (64KB)
  unsigned short* PiB = (unsigned short*)d_ws;
  unsigned short* PjB = PiB + 8 * 256 * 256;
  unsigned short* W2T = PjB + 8 * 256 * 256;

  k_proj<<<529, 256, 0, stream>>>(x, W1, b1, W2, out, PiB, PjB, W2T);
  k_main<<<2048, 1024, 0, stream>>>(PiB, PjB, W2T, b2, W3, b3, out + 2048);
}

// Round 6
// 118.405 us; speedup vs baseline: 1.5114x; 1.0755x over previous
//
#include <hip/hip_runtime.h>

// B=8, N=256, D=128, 2D=256.
// out = tour [8,256] (arange) ++ improvement_matrix [8,256,256].

typedef __attribute__((ext_vector_type(8))) short short8;
typedef __attribute__((ext_vector_type(4))) float floatx4;

static __device__ __forceinline__ unsigned short f2bf(float f) {
  unsigned int x = __float_as_uint(f);
  x += 0x7fff + ((x >> 16) & 1);   // RNE fp32 -> bf16
  return (unsigned short)(x >> 16);
}

static __device__ __forceinline__ float fast_tanh(float x) {
  float e = __expf(2.0f * fabsf(x));                       // e^{2|x|}
  float t = 1.0f - 2.0f * __builtin_amdgcn_rcpf(e + 1.0f); // in [0,1)
  return copysignf(t, x);
}

// ---- k_prep: tour out | W2->bf16 T | W1->bf16 T | xcat bf16 ---------------
// W1T[n][k] (n<512,k<256) = W1[k + (n>=256?256:0)][n&255]  (bf16)
// xcat[r][k] (r=b*256+pos): k<128 -> x[b][pos][k]; else x[b][(pos+1)%256][k-128]
__global__ __launch_bounds__(256) void k_prep(
    const float* __restrict__ x, const float* __restrict__ W1,
    const float* __restrict__ W2, float* __restrict__ out,
    unsigned short* __restrict__ W2T, unsigned short* __restrict__ W1T,
    unsigned short* __restrict__ xcat) {
  int e = blockIdx.x * 256 + threadIdx.x;   // grid covers 690176
  if (e < 2048) {
    out[e] = (float)(e & 255);              // improved_tour rows = arange
  } else if (e < 34816) {
    int e2 = e - 2048;                      // 32768: W2 [256 k][128 n]
    int k = e2 >> 7, n = e2 & 127;
    W2T[n * 256 + k] = f2bf(W2[e2]);
  } else if (e < 165888) {
    int e3 = e - 34816;                     // 131072: W1T [512 n][256 k]
    int n = e3 >> 8, k = e3 & 255;
    W1T[e3] = f2bf(W1[((k + (n & 256)) << 8) + (n & 255)]);
  } else {
    int e4 = e - 165888;                    // 524288: xcat [2048 r][256 k]
    int r = e4 >> 8, k = e4 & 255;
    int pos = r & 255;
    int pos2 = (k < 128) ? pos : ((pos + 1) & 255);
    xcat[e4] = f2bf(x[(((r >> 8) << 8) + pos2) * 128 + (k & 127)]);
  }
}

// ---- k_proj: MFMA GEMM  [2048 rows x 256 K] @ [K x 512 ch] -> PiB | PjB ----
// Block = 64 rows x 64 channels, 4 waves (wave = 16 ch x 64 rows). Pi side
// (ch<256) gets +b1 folded in. Outputs bf16.
__global__ __launch_bounds__(256) void k_proj(
    const unsigned short* __restrict__ xcat, const unsigned short* __restrict__ W1T,
    const float* __restrict__ b1, unsigned short* __restrict__ PiB,
    unsigned short* __restrict__ PjB) {
  const int mg = blockIdx.x >> 3;       // 0..31 row-tile
  const int ng = blockIdx.x & 7;        // 0..7 channel-tile
  const int tid = threadIdx.x;
  const int wr = tid >> 6, lane = tid & 63, quad = lane >> 4, l15 = lane & 15;

  __shared__ unsigned short As[64 * 256];   // 32KB rows tile (swizzled)
  __shared__ unsigned short Bs[64 * 256];   // 32KB W1T tile (swizzled)

#pragma unroll
  for (int it = 0; it < 8; ++it) {
    int e = it * 256 + tid;
    int r = e >> 5, v = e & 31;
    int col = ((v & 16) | ((v ^ (r & 15)) & 15)) << 3;
    *(uint4*)&As[r * 256 + col] = *(const uint4*)(xcat + (mg * 64 + r) * 256 + v * 8);
    *(uint4*)&Bs[r * 256 + col] = *(const uint4*)(W1T + (ng * 64 + r) * 256 + v * 8);
  }
  __syncthreads();

  floatx4 acc[4];
#pragma unroll
  for (int mt = 0; mt < 4; ++mt) acc[mt] = (floatx4)0.f;

  const char* Ab = (const char*)As;
  const char* Bb = (const char*)Bs + wr * 16 * 512;
  const int base_sw = l15 * 512 + ((quad ^ l15) << 4);

#pragma unroll
  for (int ks = 0; ks < 8; ++ks) {
    const int swz = base_sw ^ (ks << 6);
    short8 bfr = *(const short8*)(Bb + swz);
#pragma unroll
    for (int mt = 0; mt < 4; ++mt) {
      short8 afr = *(const short8*)(Ab + mt * 8192 + swz);
      acc[mt] = __builtin_amdgcn_mfma_f32_16x16x32_bf16(afr, bfr, acc[mt], 0, 0, 0);
    }
  }

  const int ch = ng * 64 + wr * 16 + l15;          // 0..511 (wave-uniform side)
  const float bias = (ch < 256) ? b1[ch] : 0.f;
  unsigned short* dst = (ch < 256) ? PiB : PjB;
  const int chan = ch & 255;
#pragma unroll
  for (int mt = 0; mt < 4; ++mt)
#pragma unroll
    for (int r = 0; r < 4; ++r) {
      int row = mg * 64 + mt * 16 + quad * 4 + r;  // global row b*256+pos
      dst[row * 256 + chan] = f2bf(acc[mt][r] + bias);
    }
}

// ---- k_main: 256 thr = 4 waves x 64 j; block = (b, pair {i, 255-i}) -------
// j=64/wave -> 32 MFMA-FLOP per LDS byte (LDS pipe healthy). W2 (64KB) staged
// once per block, 2 i amortize it; complementary pairing balances blocks.
// Per ks: ds_reads issued BEFORE the A-build (build covers LDS latency);
// depth-1 global prefetch spans the whole ~500-cyc iteration.
__global__ __launch_bounds__(256, 2) void k_main(
    const unsigned short* __restrict__ PiB, const unsigned short* __restrict__ PjB,
    const unsigned short* __restrict__ W2T, const float* __restrict__ b2,
    const float* __restrict__ W3, const float* __restrict__ b3,
    float* __restrict__ outm) {
  const int bid = blockIdx.x;           // 1024 = 8 b * 128 pairs
  const int b = bid >> 7;
  const int ig = bid & 127;
  const int tid = threadIdx.x;
  const int wr = tid >> 6, lane = tid & 63, quad = lane >> 4, l15 = lane & 15;

  __shared__ unsigned short W2s[128][256];   // [n][k'] swizzled, 64KB

#pragma unroll
  for (int it = 0; it < 16; ++it) {
    int e = it * 256 + tid;
    int n = e >> 5, v = e & 31;
    int col = ((v & 16) | ((v ^ (n & 15)) & 15)) << 3;
    *(uint4*)&W2s[n][col] = *(const uint4*)(W2T + n * 256 + v * 8);
  }
  __syncthreads();

  // epilogue constants
  const float b3v = b3[0];
  float w3v[8], b2v[8];
#pragma unroll
  for (int nt = 0; nt < 8; ++nt) {
    w3v[nt] = W3[nt * 16 + l15];
    b2v[nt] = b2[nt * 16 + l15];
  }

  const char* W2base = (const char*)&W2s[0][0];
  const int base_sw = l15 * 512 + ((quad ^ l15) << 4);
  const unsigned short* Pjb = PjB + ((b << 8) + wr * 64 + l15) * 256 + quad * 8;

#pragma unroll
  for (int ii = 0; ii < 2; ++ii) {
    const int i = ii ? (255 - ig) : ig;
    float* orow = outm + ((b << 8) + i) * 256 + wr * 64;
    if (i > wr * 64 + 61) {              // whole wave's 64 j invalid for this i
      orow[lane] = 0.f;
      continue;
    }

    floatx4 acc[4][8];
#pragma unroll
    for (int mt = 0; mt < 4; ++mt)
#pragma unroll
      for (int nt = 0; nt < 8; ++nt) acc[mt][nt] = (floatx4)0.f;

    const unsigned short* PiRow = PiB + ((b << 8) + i) * 256 + quad * 8;

    uint4 piR[2], pjR[2][4];
    piR[0] = *(const uint4*)(PiRow);
#pragma unroll
    for (int mt = 0; mt < 4; ++mt) pjR[0][mt] = *(const uint4*)(Pjb + mt * 4096);

#pragma unroll
    for (int ks = 0; ks < 8; ++ks) {
      const int cur = ks & 1, nxt = cur ^ 1;
      // (1) this iteration's 8 B-fragment LDS reads — latency hidden by build
      short8 bfr[8];
      const char* baddr = W2base + (base_sw ^ (ks << 6));
#pragma unroll
      for (int nt = 0; nt < 8; ++nt) bfr[nt] = *(const short8*)(baddr + nt * 8192);
      // (2) depth-1 global prefetch for ks+1
      if (ks < 7) {
        piR[nxt] = *(const uint4*)(PiRow + (ks + 1) * 32);
#pragma unroll
        for (int mt = 0; mt < 4; ++mt)
          pjR[nxt][mt] = *(const uint4*)(Pjb + mt * 4096 + (ks + 1) * 32);
      }
      // (3) build A-frags: relu(Pi + Pj) -> packed bf16 (truncate via perm)
      float pif[8];
#pragma unroll
      for (int p = 0; p < 4; ++p) {
        unsigned w = ((const unsigned*)&piR[cur])[p];
        pif[2 * p]     = __uint_as_float(w << 16);
        pif[2 * p + 1] = __uint_as_float(w & 0xffff0000u);
      }
      short8 af[4];
#pragma unroll
      for (int mt = 0; mt < 4; ++mt) {
        union { unsigned u[4]; short8 s; } cvt;
#pragma unroll
        for (int p = 0; p < 4; ++p) {
          unsigned w = ((const unsigned*)&pjR[cur][mt])[p];
          float lo = fmaxf(pif[2 * p]     + __uint_as_float(w << 16), 0.f);
          float hi = fmaxf(pif[2 * p + 1] + __uint_as_float(w & 0xffff0000u), 0.f);
          cvt.u[p] = __builtin_amdgcn_perm(__float_as_uint(hi), __float_as_uint(lo),
                                           0x07060302u);
        }
        af[mt] = cvt.s;
      }
      // (4) MFMA burst: 8 n-tiles x 4 m-tiles
#pragma unroll
      for (int nt = 0; nt < 8; ++nt) {
        acc[0][nt] = __builtin_amdgcn_mfma_f32_16x16x32_bf16(af[0], bfr[nt], acc[0][nt], 0, 0, 0);
        acc[1][nt] = __builtin_amdgcn_mfma_f32_16x16x32_bf16(af[1], bfr[nt], acc[1][nt], 0, 0, 0);
        acc[2][nt] = __builtin_amdgcn_mfma_f32_16x16x32_bf16(af[2], bfr[nt], acc[2][nt], 0, 0, 0);
        acc[3][nt] = __builtin_amdgcn_mfma_f32_16x16x32_bf16(af[3], bfr[nt], acc[3][nt], 0, 0, 0);
      }
    }

    // epilogue: score[j] = tanh(sum_n W3[n]*relu(C[j,n]+b2[n]) + b3), masked
#pragma unroll
    for (int mt = 0; mt < 4; ++mt) {
      float p0 = 0, p1 = 0, p2 = 0, p3 = 0;
#pragma unroll
      for (int nt = 0; nt < 8; ++nt) {
        floatx4 a = acc[mt][nt];
        p0 += fmaxf(a[0] + b2v[nt], 0.f) * w3v[nt];
        p1 += fmaxf(a[1] + b2v[nt], 0.f) * w3v[nt];
        p2 += fmaxf(a[2] + b2v[nt], 0.f) * w3v[nt];
        p3 += fmaxf(a[3] + b2v[nt], 0.f) * w3v[nt];
      }
#pragma unroll
      for (int m = 8; m >= 1; m >>= 1) {
        p0 += __shfl_xor(p0, m, 16);
        p1 += __shfl_xor(p1, m, 16);
        p2 += __shfl_xor(p2, m, 16);
        p3 += __shfl_xor(p3, m, 16);
      }
      if (l15 == 0) {
        const int jl = wr * 64 + mt * 16 + quad * 4;
        float ps[4] = {p0, p1, p2, p3};
#pragma unroll
        for (int r = 0; r < 4; ++r) {
          int j = jl + r;
          float s = fast_tanh(ps[r] + b3v);
          bool valid = (j >= i + 2) && (j - i != 255);
          orow[mt * 16 + quad * 4 + r] = valid ? s : 0.f;
        }
      }
    }
  }
}

extern "C" void kernel_launch(void* const* d_in, const int* in_sizes, int n_in,
                              void* d_out, int out_size, void* d_ws, size_t ws_size,
                              hipStream_t stream) {
  const float* x  = (const float*)d_in[0];   // [8,256,128]
  const float* W1 = (const float*)d_in[1];   // [512,256]
  const float* b1 = (const float*)d_in[2];   // [256]
  const float* W2 = (const float*)d_in[3];   // [256,128]
  const float* b2 = (const float*)d_in[4];   // [128]
  const float* W3 = (const float*)d_in[5];   // [128]
  const float* b3 = (const float*)d_in[6];   // [1]
  float* out = (float*)d_out;

  // ws (ushort units): PiB 524288 | PjB 524288 | W2T 32768 | W1T 131072 | xcat 524288
  unsigned short* PiB  = (unsigned short*)d_ws;
  unsigned short* PjB  = PiB + 524288;
  unsigned short* W2T  = PjB + 524288;
  unsigned short* W1T  = W2T + 32768;
  unsigned short* xcat = W1T + 131072;

  k_prep<<<2696, 256, 0, stream>>>(x, W1, W2, out, W2T, W1T, xcat);
  k_proj<<<256, 256, 0, stream>>>(xcat, W1T, b1, PiB, PjB);
  k_main<<<1024, 256, 0, stream>>>(PiB, PjB, W2T, b2, W3, b3, out + 2048);
}

// Round 8
// 117.323 us; speedup vs baseline: 1.5254x; 1.0092x over previous
//
#include <hip/hip_runtime.h>

// B=8, N=256, D=128, 2D=256.
// out = tour [8,256] (arange) ++ improvement_matrix [8,256,256].

typedef __attribute__((ext_vector_type(8))) short short8;
typedef __attribute__((ext_vector_type(8))) _Float16 half8;
typedef __attribute__((ext_vector_type(4))) float floatx4;

static __device__ __forceinline__ unsigned short f2bf(float f) {
  unsigned int x = __float_as_uint(f);
  x += 0x7fff + ((x >> 16) & 1);   // RNE fp32 -> bf16
  return (unsigned short)(x >> 16);
}

static __device__ __forceinline__ unsigned short f2h(float f) {
  _Float16 h = (_Float16)f;        // RNE fp32 -> fp16
  return __builtin_bit_cast(unsigned short, h);
}

static __device__ __forceinline__ float fast_tanh(float x) {
  float e = __expf(2.0f * fabsf(x));                       // e^{2|x|}
  float t = 1.0f - 2.0f * __builtin_amdgcn_rcpf(e + 1.0f); // in [0,1)
  return copysignf(t, x);
}

// ---- k_prep: tour out | W2->fp16 T | W1->bf16 T | xcat bf16 ---------------
// W1T[n][k] (n<512,k<256) = W1[k + (n>=256?256:0)][n&255]  (bf16)
// xcat[r][k] (r=b*256+pos): k<128 -> x[b][pos][k]; else x[b][(pos+1)%256][k-128]
__global__ __launch_bounds__(256) void k_prep(
    const float* __restrict__ x, const float* __restrict__ W1,
    const float* __restrict__ W2, float* __restrict__ out,
    unsigned short* __restrict__ W2H, unsigned short* __restrict__ W1T,
    unsigned short* __restrict__ xcat) {
  int e = blockIdx.x * 256 + threadIdx.x;   // grid covers 690176
  if (e < 2048) {
    out[e] = (float)(e & 255);              // improved_tour rows = arange
  } else if (e < 34816) {
    int e2 = e - 2048;                      // 32768: W2 [256 k][128 n]
    int k = e2 >> 7, n = e2 & 127;
    W2H[n * 256 + k] = f2h(W2[e2]);         // fp16
  } else if (e < 165888) {
    int e3 = e - 34816;                     // 131072: W1T [512 n][256 k]
    int n = e3 >> 8, k = e3 & 255;
    W1T[e3] = f2bf(W1[((k + (n & 256)) << 8) + (n & 255)]);
  } else {
    int e4 = e - 165888;                    // 524288: xcat [2048 r][256 k]
    int r = e4 >> 8, k = e4 & 255;
    int pos = r & 255;
    int pos2 = (k < 128) ? pos : ((pos + 1) & 255);
    xcat[e4] = f2bf(x[(((r >> 8) << 8) + pos2) * 128 + (k & 127)]);
  }
}

// ---- k_proj: MFMA GEMM  [2048 rows x 256 K] @ [K x 512 ch] -> PiH | PjH ----
// Block = 64 rows x 64 channels, 4 waves (wave = 16 ch x 64 rows). Pi side
// (ch<256) gets +b1 folded in. Outputs fp16.
__global__ __launch_bounds__(256) void k_proj(
    const unsigned short* __restrict__ xcat, const unsigned short* __restrict__ W1T,
    const float* __restrict__ b1, unsigned short* __restrict__ PiH,
    unsigned short* __restrict__ PjH) {
  const int mg = blockIdx.x >> 3;       // 0..31 row-tile
  const int ng = blockIdx.x & 7;        // 0..7 channel-tile
  const int tid = threadIdx.x;
  const int wr = tid >> 6, lane = tid & 63, quad = lane >> 4, l15 = lane & 15;

  __shared__ unsigned short As[64 * 256];   // 32KB rows tile (swizzled)
  __shared__ unsigned short Bs[64 * 256];   // 32KB W1T tile (swizzled)

#pragma unroll
  for (int it = 0; it < 8; ++it) {
    int e = it * 256 + tid;
    int r = e >> 5, v = e & 31;
    int col = ((v & 16) | ((v ^ (r & 15)) & 15)) << 3;
    *(uint4*)&As[r * 256 + col] = *(const uint4*)(xcat + (mg * 64 + r) * 256 + v * 8);
    *(uint4*)&Bs[r * 256 + col] = *(const uint4*)(W1T + (ng * 64 + r) * 256 + v * 8);
  }
  __syncthreads();

  floatx4 acc[4];
#pragma unroll
  for (int mt = 0; mt < 4; ++mt) acc[mt] = (floatx4)0.f;

  const char* Ab = (const char*)As;
  const char* Bb = (const char*)Bs + wr * 16 * 512;
  const int base_sw = l15 * 512 + ((quad ^ l15) << 4);

#pragma unroll
  for (int ks = 0; ks < 8; ++ks) {
    const int swz = base_sw ^ (ks << 6);
    short8 bfr = *(const short8*)(Bb + swz);
#pragma unroll
    for (int mt = 0; mt < 4; ++mt) {
      short8 afr = *(const short8*)(Ab + mt * 8192 + swz);
      acc[mt] = __builtin_amdgcn_mfma_f32_16x16x32_bf16(afr, bfr, acc[mt], 0, 0, 0);
    }
  }

  const int ch = ng * 64 + wr * 16 + l15;          // 0..511 (wave-uniform side)
  const float bias = (ch < 256) ? b1[ch] : 0.f;
  unsigned short* dst = (ch < 256) ? PiH : PjH;
  const int chan = ch & 255;
#pragma unroll
  for (int mt = 0; mt < 4; ++mt)
#pragma unroll
    for (int r = 0; r < 4; ++r) {
      int row = mg * 64 + mt * 16 + quad * 4 + r;  // global row b*256+pos
      dst[row * 256 + chan] = f2h(acc[mt][r] + bias);
    }
}

// ---- k_main: 256 thr = 4 waves x 64 j; block = (b, pair {i, 255-i}) -------
// fp16 pair-GEMM: A = relu_fp16(Pi+Pj) built with v_pk_add_f16/v_pk_max_f16
// (native _Float16 vectors; 2 packed VALU per 4 elems, no unpack/pack),
// feeding mfma_f32_16x16x32_f16. W2 fp16 panel (64KB) staged once; 2 i
// amortize; ONE barrier.
__global__ __launch_bounds__(256, 2) void k_main(
    const unsigned short* __restrict__ PiH, const unsigned short* __restrict__ PjH,
    const unsigned short* __restrict__ W2H, const float* __restrict__ b2,
    const float* __restrict__ W3, const float* __restrict__ b3,
    float* __restrict__ outm) {
  const int bid = blockIdx.x;           // 1024 = 8 b * 128 pairs
  const int b = bid >> 7;
  const int ig = bid & 127;
  const int tid = threadIdx.x;
  const int wr = tid >> 6, lane = tid & 63, quad = lane >> 4, l15 = lane & 15;

  __shared__ unsigned short W2s[128][256];   // [n][k'] swizzled, 64KB fp16

#pragma unroll
  for (int it = 0; it < 16; ++it) {
    int e = it * 256 + tid;
    int n = e >> 5, v = e & 31;
    int col = ((v & 16) | ((v ^ (n & 15)) & 15)) << 3;
    *(uint4*)&W2s[n][col] = *(const uint4*)(W2H + n * 256 + v * 8);
  }
  __syncthreads();

  // epilogue constants
  const float b3v = b3[0];
  float w3v[8], b2v[8];
#pragma unroll
  for (int nt = 0; nt < 8; ++nt) {
    w3v[nt] = W3[nt * 16 + l15];
    b2v[nt] = b2[nt * 16 + l15];
  }

  const char* W2base = (const char*)&W2s[0][0];
  const int base_sw = l15 * 512 + ((quad ^ l15) << 4);
  const unsigned short* Pjb = PjH + ((b << 8) + wr * 64 + l15) * 256 + quad * 8;

#pragma unroll
  for (int ii = 0; ii < 2; ++ii) {
    const int i = ii ? (255 - ig) : ig;
    float* orow = outm + ((b << 8) + i) * 256 + wr * 64;
    if (i > wr * 64 + 61) {              // whole wave's 64 j invalid for this i
      orow[lane] = 0.f;
      continue;
    }

    floatx4 acc[4][8];
#pragma unroll
    for (int mt = 0; mt < 4; ++mt)
#pragma unroll
      for (int nt = 0; nt < 8; ++nt) acc[mt][nt] = (floatx4)0.f;

    const unsigned short* PiRow = PiH + ((b << 8) + i) * 256 + quad * 8;

    union U4 { uint4 v; half8 h; };
    U4 piR[2], pjR[2][4];
    piR[0].v = *(const uint4*)(PiRow);
#pragma unroll
    for (int mt = 0; mt < 4; ++mt) pjR[0][mt].v = *(const uint4*)(Pjb + mt * 4096);

#pragma unroll
    for (int ks = 0; ks < 8; ++ks) {
      const int cur = ks & 1, nxt = cur ^ 1;
      // (1) this iteration's 8 B-fragment LDS reads
      half8 bfr[8];
      const char* baddr = W2base + (base_sw ^ (ks << 6));
#pragma unroll
      for (int nt = 0; nt < 8; ++nt) bfr[nt] = *(const half8*)(baddr + nt * 8192);
      // (2) depth-1 global prefetch for ks+1
      if (ks < 7) {
        piR[nxt].v = *(const uint4*)(PiRow + (ks + 1) * 32);
#pragma unroll
        for (int mt = 0; mt < 4; ++mt)
          pjR[nxt][mt].v = *(const uint4*)(Pjb + mt * 4096 + (ks + 1) * 32);
      }
      // (3) build A-frags: packed fp16 relu(Pi + Pj) — v_pk_add/max_f16
      half8 af[4];
#pragma unroll
      for (int mt = 0; mt < 4; ++mt)
        af[mt] = __builtin_elementwise_max(piR[cur].h + pjR[cur][mt].h,
                                           (half8)(_Float16)0);
      // (4) MFMA burst: 8 n-tiles x 4 m-tiles
#pragma unroll
      for (int nt = 0; nt < 8; ++nt) {
        acc[0][nt] = __builtin_amdgcn_mfma_f32_16x16x32_f16(af[0], bfr[nt], acc[0][nt], 0, 0, 0);
        acc[1][nt] = __builtin_amdgcn_mfma_f32_16x16x32_f16(af[1], bfr[nt], acc[1][nt], 0, 0, 0);
        acc[2][nt] = __builtin_amdgcn_mfma_f32_16x16x32_f16(af[2], bfr[nt], acc[2][nt], 0, 0, 0);
        acc[3][nt] = __builtin_amdgcn_mfma_f32_16x16x32_f16(af[3], bfr[nt], acc[3][nt], 0, 0, 0);
      }
    }

    // epilogue: score[j] = tanh(sum_n W3[n]*relu(C[j,n]+b2[n]) + b3), masked
#pragma unroll
    for (int mt = 0; mt < 4; ++mt) {
      float p0 = 0, p1 = 0, p2 = 0, p3 = 0;
#pragma unroll
      for (int nt = 0; nt < 8; ++nt) {
        floatx4 a = acc[mt][nt];
        p0 += fmaxf(a[0] + b2v[nt], 0.f) * w3v[nt];
        p1 += fmaxf(a[1] + b2v[nt], 0.f) * w3v[nt];
        p2 += fmaxf(a[2] + b2v[nt], 0.f) * w3v[nt];
        p3 += fmaxf(a[3] + b2v[nt], 0.f) * w3v[nt];
      }
#pragma unroll
      for (int m = 8; m >= 1; m >>= 1) {
        p0 += __shfl_xor(p0, m, 16);
        p1 += __shfl_xor(p1, m, 16);
        p2 += __shfl_xor(p2, m, 16);
        p3 += __shfl_xor(p3, m, 16);
      }
      if (l15 == 0) {
        const int jl = wr * 64 + mt * 16 + quad * 4;
        float ps[4] = {p0, p1, p2, p3};
#pragma unroll
        for (int r = 0; r < 4; ++r) {
          int j = jl + r;
          float s = fast_tanh(ps[r] + b3v);
          bool valid = (j >= i + 2) && (j - i != 255);
          orow[mt * 16 + quad * 4 + r] = valid ? s : 0.f;
        }
      }
    }
  }
}

extern "C" void kernel_launch(void* const* d_in, const int* in_sizes, int n_in,
                              void* d_out, int out_size, void* d_ws, size_t ws_size,
                              hipStream_t stream) {
  const float* x  = (const float*)d_in[0];   // [8,256,128]
  const float* W1 = (const float*)d_in[1];   // [512,256]
  const float* b1 = (const float*)d_in[2];   // [256]
  const float* W2 = (const float*)d_in[3];   // [256,128]
  const float* b2 = (const float*)d_in[4];   // [128]
  const float* W3 = (const float*)d_in[5];   // [128]
  const float* b3 = (const float*)d_in[6];   // [1]
  float* out = (float*)d_out;

  // ws (ushort units): PiH 524288 | PjH 524288 | W2H 32768 | W1T 131072 | xcat 524288
  unsigned short* PiH  = (unsigned short*)d_ws;
  unsigned short* PjH  = PiH + 524288;
  unsigned short* W2H  = PjH + 524288;
  unsigned short* W1T  = W2H + 32768;
  unsigned short* xcat = W1T + 131072;

  k_prep<<<2696, 256, 0, stream>>>(x, W1, W2, out, W2H, W1T, xcat);
  k_proj<<<256, 256, 0, stream>>>(xcat, W1T, b1, PiH, PjH);
  k_main<<<1024, 256, 0, stream>>>(PiH, PjH, W2H, b2, W3, b3, out + 2048);
}

// Round 9
// 110.736 us; speedup vs baseline: 1.6161x; 1.0595x over previous
//
#include <hip/hip_runtime.h>

// B=8, N=256, D=128, 2D=256.
// out = tour [8,256] (arange) ++ improvement_matrix [8,256,256].

typedef __attribute__((ext_vector_type(8))) short short8;
typedef __attribute__((ext_vector_type(8))) _Float16 half8;
typedef __attribute__((ext_vector_type(4))) float floatx4;

static __device__ __forceinline__ unsigned short f2bf(float f) {
  unsigned int x = __float_as_uint(f);
  x += 0x7fff + ((x >> 16) & 1);   // RNE fp32 -> bf16
  return (unsigned short)(x >> 16);
}

static __device__ __forceinline__ unsigned short f2h(float f) {
  _Float16 h = (_Float16)f;        // RNE fp32 -> fp16
  return __builtin_bit_cast(unsigned short, h);
}

static __device__ __forceinline__ float fast_tanh(float x) {
  float e = __expf(2.0f * fabsf(x));                       // e^{2|x|}
  float t = 1.0f - 2.0f * __builtin_amdgcn_rcpf(e + 1.0f); // in [0,1)
  return copysignf(t, x);
}

// ---- k_prep: tour out | W2->fp16 T | W1->bf16 T | xcat bf16 ---------------
__global__ __launch_bounds__(256) void k_prep(
    const float* __restrict__ x, const float* __restrict__ W1,
    const float* __restrict__ W2, float* __restrict__ out,
    unsigned short* __restrict__ W2H, unsigned short* __restrict__ W1T,
    unsigned short* __restrict__ xcat) {
  int e = blockIdx.x * 256 + threadIdx.x;   // grid covers 690176
  if (e < 2048) {
    out[e] = (float)(e & 255);              // improved_tour rows = arange
  } else if (e < 34816) {
    int e2 = e - 2048;                      // 32768: W2 [256 k][128 n]
    int k = e2 >> 7, n = e2 & 127;
    W2H[n * 256 + k] = f2h(W2[e2]);         // fp16
  } else if (e < 165888) {
    int e3 = e - 34816;                     // 131072: W1T [512 n][256 k]
    int n = e3 >> 8, k = e3 & 255;
    W1T[e3] = f2bf(W1[((k + (n & 256)) << 8) + (n & 255)]);
  } else {
    int e4 = e - 165888;                    // 524288: xcat [2048 r][256 k]
    int r = e4 >> 8, k = e4 & 255;
    int pos = r & 255;
    int pos2 = (k < 128) ? pos : ((pos + 1) & 255);
    xcat[e4] = f2bf(x[(((r >> 8) << 8) + pos2) * 128 + (k & 127)]);
  }
}

// ---- k_proj: MFMA GEMM  [2048 rows x 256 K] @ [K x 512 ch] -> PiH | PjH ----
__global__ __launch_bounds__(256) void k_proj(
    const unsigned short* __restrict__ xcat, const unsigned short* __restrict__ W1T,
    const float* __restrict__ b1, unsigned short* __restrict__ PiH,
    unsigned short* __restrict__ PjH) {
  const int mg = blockIdx.x >> 3;       // 0..31 row-tile
  const int ng = blockIdx.x & 7;        // 0..7 channel-tile
  const int tid = threadIdx.x;
  const int wr = tid >> 6, lane = tid & 63, quad = lane >> 4, l15 = lane & 15;

  __shared__ unsigned short As[64 * 256];   // 32KB rows tile (swizzled)
  __shared__ unsigned short Bs[64 * 256];   // 32KB W1T tile (swizzled)

#pragma unroll
  for (int it = 0; it < 8; ++it) {
    int e = it * 256 + tid;
    int r = e >> 5, v = e & 31;
    int col = ((v & 16) | ((v ^ (r & 15)) & 15)) << 3;
    *(uint4*)&As[r * 256 + col] = *(const uint4*)(xcat + (mg * 64 + r) * 256 + v * 8);
    *(uint4*)&Bs[r * 256 + col] = *(const uint4*)(W1T + (ng * 64 + r) * 256 + v * 8);
  }
  __syncthreads();

  floatx4 acc[4];
#pragma unroll
  for (int mt = 0; mt < 4; ++mt) acc[mt] = (floatx4)0.f;

  const char* Ab = (const char*)As;
  const char* Bb = (const char*)Bs + wr * 16 * 512;
  const int base_sw = l15 * 512 + ((quad ^ l15) << 4);

#pragma unroll
  for (int ks = 0; ks < 8; ++ks) {
    const int swz = base_sw ^ (ks << 6);
    short8 bfr = *(const short8*)(Bb + swz);
#pragma unroll
    for (int mt = 0; mt < 4; ++mt) {
      short8 afr = *(const short8*)(Ab + mt * 8192 + swz);
      acc[mt] = __builtin_amdgcn_mfma_f32_16x16x32_bf16(afr, bfr, acc[mt], 0, 0, 0);
    }
  }

  const int ch = ng * 64 + wr * 16 + l15;          // 0..511 (wave-uniform side)
  const float bias = (ch < 256) ? b1[ch] : 0.f;
  unsigned short* dst = (ch < 256) ? PiH : PjH;
  const int chan = ch & 255;
#pragma unroll
  for (int mt = 0; mt < 4; ++mt)
#pragma unroll
    for (int r = 0; r < 4; ++r) {
      int row = mg * 64 + mt * 16 + quad * 4 + r;  // global row b*256+pos
      dst[row * 256 + chan] = f2h(acc[mt][r] + bias);
    }
}

// ---- k_main: 512 thr = 8 waves x 32 j; block = (b, pair {i, 255-i}) -------
// fp16 pair-GEMM, acc = 64 AGPR/wave + ~60 arch <= 128-reg cap from
// __launch_bounds__(512,4); LDS 64KB -> 2 blocks/CU = 16 waves/CU (4/SIMD)
// so sibling waves cover ds_read + global latency. B-frags read one at a
// time (no bfr[] array — registers are the scarce resource, R8's spill).
__global__ __launch_bounds__(512, 4) void k_main(
    const unsigned short* __restrict__ PiH, const unsigned short* __restrict__ PjH,
    const unsigned short* __restrict__ W2H, const float* __restrict__ b2,
    const float* __restrict__ W3, const float* __restrict__ b3,
    float* __restrict__ outm) {
  const int bid = blockIdx.x;           // 1024 = 8 b * 128 pairs
  const int b = bid >> 7;
  const int ig = bid & 127;
  const int tid = threadIdx.x;
  const int wr = tid >> 6;              // wave 0..7 -> j in [wr*32, wr*32+32)
  const int lane = tid & 63, quad = lane >> 4, l15 = lane & 15;

  __shared__ unsigned short W2s[128][256];   // [n][k'] swizzled, 64KB fp16

#pragma unroll
  for (int it = 0; it < 8; ++it) {
    int e = it * 512 + tid;
    int n = e >> 5, v = e & 31;
    int col = ((v & 16) | ((v ^ (n & 15)) & 15)) << 3;
    *(uint4*)&W2s[n][col] = *(const uint4*)(W2H + n * 256 + v * 8);
  }
  __syncthreads();

  const char* W2base = (const char*)&W2s[0][0];
  const int base_sw = l15 * 512 + ((quad ^ l15) << 4);
  const unsigned short* Pjb = PjH + ((b << 8) + wr * 32 + l15) * 256 + quad * 8;

#pragma unroll
  for (int ii = 0; ii < 2; ++ii) {
    const int i = ii ? (255 - ig) : ig;
    float* orow = outm + ((b << 8) + i) * 256 + wr * 32;
    if (i > wr * 32 + 29) {              // whole wave's 32 j invalid for this i
      if (lane < 32) orow[lane] = 0.f;
      continue;
    }

    floatx4 acc[2][8];
#pragma unroll
    for (int mt = 0; mt < 2; ++mt)
#pragma unroll
      for (int nt = 0; nt < 8; ++nt) acc[mt][nt] = (floatx4)0.f;

    const unsigned short* PiRow = PiH + ((b << 8) + i) * 256 + quad * 8;

    union U4 { uint4 v; half8 h; };
    U4 piR[2], pjR[2][2];
    piR[0].v = *(const uint4*)(PiRow);
    pjR[0][0].v = *(const uint4*)(Pjb);
    pjR[0][1].v = *(const uint4*)(Pjb + 4096);   // mt=1: +16 rows

#pragma unroll
    for (int ks = 0; ks < 8; ++ks) {
      const int cur = ks & 1, nxt = cur ^ 1;
      if (ks < 7) {                    // depth-1 global prefetch
        piR[nxt].v = *(const uint4*)(PiRow + (ks + 1) * 32);
        pjR[nxt][0].v = *(const uint4*)(Pjb + (ks + 1) * 32);
        pjR[nxt][1].v = *(const uint4*)(Pjb + 4096 + (ks + 1) * 32);
      }
      // build A-frags: packed fp16 relu(Pi + Pj) — v_pk_add/max_f16
      const half8 af0 = __builtin_elementwise_max(piR[cur].h + pjR[cur][0].h,
                                                  (half8)(_Float16)0);
      const half8 af1 = __builtin_elementwise_max(piR[cur].h + pjR[cur][1].h,
                                                  (half8)(_Float16)0);
      const char* baddr = W2base + (base_sw ^ (ks << 6));
#pragma unroll
      for (int nt = 0; nt < 8; ++nt) {
        half8 bfr = *(const half8*)(baddr + nt * 8192);
        acc[0][nt] = __builtin_amdgcn_mfma_f32_16x16x32_f16(af0, bfr, acc[0][nt], 0, 0, 0);
        acc[1][nt] = __builtin_amdgcn_mfma_f32_16x16x32_f16(af1, bfr, acc[1][nt], 0, 0, 0);
      }
    }

    // epilogue: score[j] = tanh(sum_n W3[n]*relu(C[j,n]+b2[n]) + b3), masked
    const float b3v = b3[0];
#pragma unroll
    for (int mt = 0; mt < 2; ++mt) {
      float p0 = 0, p1 = 0, p2 = 0, p3 = 0;
#pragma unroll
      for (int nt = 0; nt < 8; ++nt) {
        float w3v = W3[nt * 16 + l15];
        float b2v = b2[nt * 16 + l15];
        floatx4 a = acc[mt][nt];
        p0 += fmaxf(a[0] + b2v, 0.f) * w3v;
        p1 += fmaxf(a[1] + b2v, 0.f) * w3v;
        p2 += fmaxf(a[2] + b2v, 0.f) * w3v;
        p3 += fmaxf(a[3] + b2v, 0.f) * w3v;
      }
#pragma unroll
      for (int m = 8; m >= 1; m >>= 1) {   // reduce over the 16 n-cols per quad
        p0 += __shfl_xor(p0, m, 16);
        p1 += __shfl_xor(p1, m, 16);
        p2 += __shfl_xor(p2, m, 16);
        p3 += __shfl_xor(p3, m, 16);
      }
      if (l15 == 0) {
        const int jl = wr * 32 + mt * 16 + quad * 4;
        float ps[4] = {p0, p1, p2, p3};
#pragma unroll
        for (int r = 0; r < 4; ++r) {
          int j = jl + r;
          float s = fast_tanh(ps[r] + b3v);
          bool valid = (j >= i + 2) && (j - i != 255);
          orow[mt * 16 + quad * 4 + r] = valid ? s : 0.f;
        }
      }
    }
  }
}

extern "C" void kernel_launch(void* const* d_in, const int* in_sizes, int n_in,
                              void* d_out, int out_size, void* d_ws, size_t ws_size,
                              hipStream_t stream) {
  const float* x  = (const float*)d_in[0];   // [8,256,128]
  const float* W1 = (const float*)d_in[1];   // [512,256]
  const float* b1 = (const float*)d_in[2];   // [256]
  const float* W2 = (const float*)d_in[3];   // [256,128]
  const float* b2 = (const float*)d_in[4];   // [128]
  const float* W3 = (const float*)d_in[5];   // [128]
  const float* b3 = (const float*)d_in[6];   // [1]
  float* out = (float*)d_out;

  // ws (ushort units): PiH 524288 | PjH 524288 | W2H 32768 | W1T 131072 | xcat 524288
  unsigned short* PiH  = (unsigned short*)d_ws;
  unsigned short* PjH  = PiH + 524288;
  unsigned short* W2H  = PjH + 524288;
  unsigned short* W1T  = W2H + 32768;
  unsigned short* xcat = W1T + 131072;

  k_prep<<<2696, 256, 0, stream>>>(x, W1, W2, out, W2H, W1T, xcat);
  k_proj<<<256, 256, 0, stream>>>(xcat, W1T, b1, PiH, PjH);
  k_main<<<1024, 512, 0, stream>>>(PiH, PjH, W2H, b2, W3, b3, out + 2048);
}

// Round 10
// 105.946 us; speedup vs baseline: 1.6891x; 1.0452x over previous
//
#include <hip/hip_runtime.h>

// B=8, N=256, D=128, 2D=256.
// out = tour [8,256] (arange) ++ improvement_matrix [8,256,256].

typedef __attribute__((ext_vector_type(8))) short short8;
typedef __attribute__((ext_vector_type(8))) _Float16 half8;
typedef __attribute__((ext_vector_type(4))) float floatx4;

static __device__ __forceinline__ unsigned short f2bf(float f) {
  unsigned int x = __float_as_uint(f);
  x += 0x7fff + ((x >> 16) & 1);   // RNE fp32 -> bf16
  return (unsigned short)(x >> 16);
}

static __device__ __forceinline__ unsigned short f2h(float f) {
  _Float16 h = (_Float16)f;        // RNE fp32 -> fp16
  return __builtin_bit_cast(unsigned short, h);
}

static __device__ __forceinline__ float fast_tanh(float x) {
  float e = __expf(2.0f * fabsf(x));                       // e^{2|x|}
  float t = 1.0f - 2.0f * __builtin_amdgcn_rcpf(e + 1.0f); // in [0,1)
  return copysignf(t, x);
}

// ---- k_prep: tour | zero matrix | W2->fp16 T | W1->bf16 T | xcat bf16 -----
__global__ __launch_bounds__(256) void k_prep(
    const float* __restrict__ x, const float* __restrict__ W1,
    const float* __restrict__ W2, float* __restrict__ out,
    unsigned short* __restrict__ W2H, unsigned short* __restrict__ W1T,
    unsigned short* __restrict__ xcat) {
  int e = blockIdx.x * 256 + threadIdx.x;   // grid covers 1214464
  if (e < 2048) {
    out[e] = (float)(e & 255);              // improved_tour rows = arange
  } else if (e < 526336) {
    out[e] = 0.f;                           // zero matrix (uncovered tiles)
  } else if (e < 559104) {
    int e2 = e - 526336;                    // 32768: W2 [256 k][128 n]
    int k = e2 >> 7, n = e2 & 127;
    W2H[n * 256 + k] = f2h(W2[e2]);         // fp16
  } else if (e < 690176) {
    int e3 = e - 559104;                    // 131072: W1T [512 n][256 k]
    int n = e3 >> 8, k = e3 & 255;
    W1T[e3] = f2bf(W1[((k + (n & 256)) << 8) + (n & 255)]);
  } else {
    int e4 = e - 690176;                    // 524288: xcat [2048 r][256 k]
    int r = e4 >> 8, k = e4 & 255;
    int pos = r & 255;
    int pos2 = (k < 128) ? pos : ((pos + 1) & 255);
    xcat[e4] = f2bf(x[(((r >> 8) << 8) + pos2) * 128 + (k & 127)]);
  }
}

// ---- k_proj: MFMA GEMM  [2048 rows x 256 K] @ [K x 512 ch] -> PiH | PjH ----
__global__ __launch_bounds__(256) void k_proj(
    const unsigned short* __restrict__ xcat, const unsigned short* __restrict__ W1T,
    const float* __restrict__ b1, unsigned short* __restrict__ PiH,
    unsigned short* __restrict__ PjH) {
  const int mg = blockIdx.x >> 3;       // 0..31 row-tile
  const int ng = blockIdx.x & 7;        // 0..7 channel-tile
  const int tid = threadIdx.x;
  const int wr = tid >> 6, lane = tid & 63, quad = lane >> 4, l15 = lane & 15;

  __shared__ unsigned short As[64 * 256];   // 32KB rows tile (swizzled)
  __shared__ unsigned short Bs[64 * 256];   // 32KB W1T tile (swizzled)

#pragma unroll
  for (int it = 0; it < 8; ++it) {
    int e = it * 256 + tid;
    int r = e >> 5, v = e & 31;
    int col = ((v & 16) | ((v ^ (r & 15)) & 15)) << 3;
    *(uint4*)&As[r * 256 + col] = *(const uint4*)(xcat + (mg * 64 + r) * 256 + v * 8);
    *(uint4*)&Bs[r * 256 + col] = *(const uint4*)(W1T + (ng * 64 + r) * 256 + v * 8);
  }
  __syncthreads();

  floatx4 acc[4];
#pragma unroll
  for (int mt = 0; mt < 4; ++mt) acc[mt] = (floatx4)0.f;

  const char* Ab = (const char*)As;
  const char* Bb = (const char*)Bs + wr * 16 * 512;
  const int base_sw = l15 * 512 + ((quad ^ l15) << 4);

#pragma unroll
  for (int ks = 0; ks < 8; ++ks) {
    const int swz = base_sw ^ (ks << 6);
    short8 bfr = *(const short8*)(Bb + swz);
#pragma unroll
    for (int mt = 0; mt < 4; ++mt) {
      short8 afr = *(const short8*)(Ab + mt * 8192 + swz);
      acc[mt] = __builtin_amdgcn_mfma_f32_16x16x32_bf16(afr, bfr, acc[mt], 0, 0, 0);
    }
  }

  const int ch = ng * 64 + wr * 16 + l15;          // 0..511 (wave-uniform side)
  const float bias = (ch < 256) ? b1[ch] : 0.f;
  unsigned short* dst = (ch < 256) ? PiH : PjH;
  const int chan = ch & 255;
#pragma unroll
  for (int mt = 0; mt < 4; ++mt)
#pragma unroll
    for (int r = 0; r < 4; ++r) {
      int row = mg * 64 + mt * 16 + quad * 4 + r;  // global row b*256+pos
      dst[row * 256 + chan] = f2h(acc[mt][r] + bias);
    }
}

// ---- k_main: packed work items. Item = (i, jt) with jt*32+29 >= i (tile of
// 32 j's containing >=1 valid pair). 1136 items per b, prefix
// P = {0,30,92,186,312,470,660,882} by jt. Grid (142, 8b); block = 8 waves,
// wave wr handles item blockIdx.x*8+wr -> ZERO skipped waves, uniform work.
// fp16 pair-GEMM, acc = 64 AGPR + ~64 arch fits (512,4)'s 128-reg cap ->
// 2 blocks/CU (LDS) = 16 waves/CU. W2 (64KB fp16) staged once; ONE barrier.
__global__ __launch_bounds__(512, 4) void k_main(
    const unsigned short* __restrict__ PiH, const unsigned short* __restrict__ PjH,
    const unsigned short* __restrict__ W2H, const float* __restrict__ b2,
    const float* __restrict__ W3, const float* __restrict__ b3,
    float* __restrict__ outm) {
  const int b = blockIdx.y;
  const int tid = threadIdx.x;
  const int wr = tid >> 6;              // wave 0..7
  const int lane = tid & 63, quad = lane >> 4, l15 = lane & 15;

  __shared__ unsigned short W2s[128][256];   // [n][k'] swizzled, 64KB fp16

#pragma unroll
  for (int it = 0; it < 8; ++it) {
    int e = it * 512 + tid;
    int n = e >> 5, v = e & 31;
    int col = ((v & 16) | ((v ^ (n & 15)) & 15)) << 3;
    *(uint4*)&W2s[n][col] = *(const uint4*)(W2H + n * 256 + v * 8);
  }
  __syncthreads();

  // decode packed item e -> (jt, i)   [wave-uniform scalar ops]
  const int e = blockIdx.x * 8 + wr;       // 0..1135
  int jt = 0, base = 0;
  if (e >= 30)  { jt = 1; base = 30;  }
  if (e >= 92)  { jt = 2; base = 92;  }
  if (e >= 186) { jt = 3; base = 186; }
  if (e >= 312) { jt = 4; base = 312; }
  if (e >= 470) { jt = 5; base = 470; }
  if (e >= 660) { jt = 6; base = 660; }
  if (e >= 882) { jt = 7; base = 882; }
  const int i = e - base;                  // 0 .. jt*32+29

  const char* W2base = (const char*)&W2s[0][0];
  const int base_sw = l15 * 512 + ((quad ^ l15) << 4);
  const unsigned short* Pjb = PjH + ((b << 8) + jt * 32 + l15) * 256 + quad * 8;
  const unsigned short* PiRow = PiH + ((b << 8) + i) * 256 + quad * 8;

  floatx4 acc[2][8];
#pragma unroll
  for (int mt = 0; mt < 2; ++mt)
#pragma unroll
    for (int nt = 0; nt < 8; ++nt) acc[mt][nt] = (floatx4)0.f;

  union U4 { uint4 v; half8 h; };
  U4 piR[2], pjR[2][2];
  piR[0].v = *(const uint4*)(PiRow);
  pjR[0][0].v = *(const uint4*)(Pjb);
  pjR[0][1].v = *(const uint4*)(Pjb + 4096);   // mt=1: +16 rows

#pragma unroll
  for (int ks = 0; ks < 8; ++ks) {
    const int cur = ks & 1, nxt = cur ^ 1;
    if (ks < 7) {                    // depth-1 global prefetch
      piR[nxt].v = *(const uint4*)(PiRow + (ks + 1) * 32);
      pjR[nxt][0].v = *(const uint4*)(Pjb + (ks + 1) * 32);
      pjR[nxt][1].v = *(const uint4*)(Pjb + 4096 + (ks + 1) * 32);
    }
    // build A-frags: packed fp16 relu(Pi + Pj) — v_pk_add/max_f16
    const half8 af0 = __builtin_elementwise_max(piR[cur].h + pjR[cur][0].h,
                                                (half8)(_Float16)0);
    const half8 af1 = __builtin_elementwise_max(piR[cur].h + pjR[cur][1].h,
                                                (half8)(_Float16)0);
    const char* baddr = W2base + (base_sw ^ (ks << 6));
#pragma unroll
    for (int nt = 0; nt < 8; ++nt) {
      half8 bfr = *(const half8*)(baddr + nt * 8192);
      acc[0][nt] = __builtin_amdgcn_mfma_f32_16x16x32_f16(af0, bfr, acc[0][nt], 0, 0, 0);
      acc[1][nt] = __builtin_amdgcn_mfma_f32_16x16x32_f16(af1, bfr, acc[1][nt], 0, 0, 0);
    }
  }

  // epilogue: score[j] = tanh(sum_n W3[n]*relu(C[j,n]+b2[n]) + b3), masked
  float* orow = outm + ((b << 8) + i) * 256 + jt * 32;
  const float b3v = b3[0];
#pragma unroll
  for (int mt = 0; mt < 2; ++mt) {
    float p0 = 0, p1 = 0, p2 = 0, p3 = 0;
#pragma unroll
    for (int nt = 0; nt < 8; ++nt) {
      float w3v = W3[nt * 16 + l15];
      float b2v = b2[nt * 16 + l15];
      floatx4 a = acc[mt][nt];
      p0 += fmaxf(a[0] + b2v, 0.f) * w3v;
      p1 += fmaxf(a[1] + b2v, 0.f) * w3v;
      p2 += fmaxf(a[2] + b2v, 0.f) * w3v;
      p3 += fmaxf(a[3] + b2v, 0.f) * w3v;
    }
#pragma unroll
    for (int m = 8; m >= 1; m >>= 1) {   // reduce over the 16 n-cols per quad
      p0 += __shfl_xor(p0, m, 16);
      p1 += __shfl_xor(p1, m, 16);
      p2 += __shfl_xor(p2, m, 16);
      p3 += __shfl_xor(p3, m, 16);
    }
    if (l15 == 0) {
      const int jl = jt * 32 + mt * 16 + quad * 4;   // global j of reg 0
      float ps[4] = {p0, p1, p2, p3};
#pragma unroll
      for (int r = 0; r < 4; ++r) {
        int j = jl + r;
        float s = fast_tanh(ps[r] + b3v);
        bool valid = (j >= i + 2) && (j - i != 255);
        orow[mt * 16 + quad * 4 + r] = valid ? s : 0.f;
      }
    }
  }
}

extern "C" void kernel_launch(void* const* d_in, const int* in_sizes, int n_in,
                              void* d_out, int out_size, void* d_ws, size_t ws_size,
                              hipStream_t stream) {
  const float* x  = (const float*)d_in[0];   // [8,256,128]
  const float* W1 = (const float*)d_in[1];   // [512,256]
  const float* b1 = (const float*)d_in[2];   // [256]
  const float* W2 = (const float*)d_in[3];   // [256,128]
  const float* b2 = (const float*)d_in[4];   // [128]
  const float* W3 = (const float*)d_in[5];   // [128]
  const float* b3 = (const float*)d_in[6];   // [1]
  float* out = (float*)d_out;

  // ws (ushort units): PiH 524288 | PjH 524288 | W2H 32768 | W1T 131072 | xcat 524288
  unsigned short* PiH  = (unsigned short*)d_ws;
  unsigned short* PjH  = PiH + 524288;
  unsigned short* W2H  = PjH + 524288;
  unsigned short* W1T  = W2H + 32768;
  unsigned short* xcat = W1T + 131072;

  k_prep<<<4744, 256, 0, stream>>>(x, W1, W2, out, W2H, W1T, xcat);
  k_proj<<<256, 256, 0, stream>>>(xcat, W1T, b1, PiH, PjH);
  dim3 grid_main(142, 8);
  k_main<<<grid_main, 512, 0, stream>>>(PiH, PjH, W2H, b2, W3, b3, out + 2048);
}

// Round 11
// 105.327 us; speedup vs baseline: 1.6991x; 1.0059x over previous
//
#include <hip/hip_runtime.h>

// B=8, N=256, D=128, 2D=256.
// out = tour [8,256] (arange) ++ improvement_matrix [8,256,256].

typedef __attribute__((ext_vector_type(8))) short short8;
typedef __attribute__((ext_vector_type(8))) _Float16 half8;
typedef __attribute__((ext_vector_type(4))) float floatx4;

static __device__ __forceinline__ unsigned short f2bf(float f) {
  unsigned int x = __float_as_uint(f);
  x += 0x7fff + ((x >> 16) & 1);   // RNE fp32 -> bf16
  return (unsigned short)(x >> 16);
}

static __device__ __forceinline__ unsigned short f2h(float f) {
  _Float16 h = (_Float16)f;        // RNE fp32 -> fp16
  return __builtin_bit_cast(unsigned short, h);
}

static __device__ __forceinline__ float fast_tanh(float x) {
  float e = __expf(2.0f * fabsf(x));                       // e^{2|x|}
  float t = 1.0f - 2.0f * __builtin_amdgcn_rcpf(e + 1.0f); // in [0,1)
  return copysignf(t, x);
}

// pack 8 fp16 -> 8 OCP e4m3 bytes (via f32, v_cvt_pk_fp8_f32)
static __device__ __forceinline__ long pack_fp8(half8 s) {
  int lo = __builtin_amdgcn_cvt_pk_fp8_f32((float)s[0], (float)s[1], 0, false);
  lo = __builtin_amdgcn_cvt_pk_fp8_f32((float)s[2], (float)s[3], lo, true);
  int hi = __builtin_amdgcn_cvt_pk_fp8_f32((float)s[4], (float)s[5], 0, false);
  hi = __builtin_amdgcn_cvt_pk_fp8_f32((float)s[6], (float)s[7], hi, true);
  return (long)(unsigned)lo | ((long)hi << 32);
}

// ---- k_prep: tour | zero matrix | W2->fp8(x16) T | W1->bf16 T | xcat bf16 --
__global__ __launch_bounds__(256) void k_prep(
    const float* __restrict__ x, const float* __restrict__ W1,
    const float* __restrict__ W2, float* __restrict__ out,
    unsigned char* __restrict__ W2F8, unsigned short* __restrict__ W1T,
    unsigned short* __restrict__ xcat) {
  int e = blockIdx.x * 256 + threadIdx.x;   // grid covers 1198080
  if (e < 2048) {
    out[e] = (float)(e & 255);              // improved_tour rows = arange
  } else if (e < 526336) {
    out[e] = 0.f;                           // zero matrix (uncovered tiles)
  } else if (e < 542720) {
    int t = e - 526336;                     // 16384 k-pairs of W2
    int p = t >> 7, n = t & 127;            // p = k/2, n = out channel
    float f0 = W2[(2 * p) * 128 + n] * 16.f;       // x16: into e4m3 normal range
    float f1 = W2[(2 * p + 1) * 128 + n] * 16.f;
    int v = __builtin_amdgcn_cvt_pk_fp8_f32(f0, f1, 0, false);
    *(unsigned short*)(W2F8 + n * 256 + 2 * p) = (unsigned short)(v & 0xffff);
  } else if (e < 673792) {
    int e3 = e - 542720;                    // 131072: W1T [512 n][256 k]
    int n = e3 >> 8, k = e3 & 255;
    W1T[e3] = f2bf(W1[((k + (n & 256)) << 8) + (n & 255)]);
  } else {
    int e4 = e - 673792;                    // 524288: xcat [2048 r][256 k]
    int r = e4 >> 8, k = e4 & 255;
    int pos = r & 255;
    int pos2 = (k < 128) ? pos : ((pos + 1) & 255);
    xcat[e4] = f2bf(x[(((r >> 8) << 8) + pos2) * 128 + (k & 127)]);
  }
}

// ---- k_proj: MFMA GEMM  [2048 rows x 256 K] @ [K x 512 ch] -> PiH | PjH ----
__global__ __launch_bounds__(256) void k_proj(
    const unsigned short* __restrict__ xcat, const unsigned short* __restrict__ W1T,
    const float* __restrict__ b1, unsigned short* __restrict__ PiH,
    unsigned short* __restrict__ PjH) {
  const int mg = blockIdx.x >> 3;       // 0..31 row-tile
  const int ng = blockIdx.x & 7;        // 0..7 channel-tile
  const int tid = threadIdx.x;
  const int wr = tid >> 6, lane = tid & 63, quad = lane >> 4, l15 = lane & 15;

  __shared__ unsigned short As[64 * 256];   // 32KB rows tile (swizzled)
  __shared__ unsigned short Bs[64 * 256];   // 32KB W1T tile (swizzled)

#pragma unroll
  for (int it = 0; it < 8; ++it) {
    int e = it * 256 + tid;
    int r = e >> 5, v = e & 31;
    int col = ((v & 16) | ((v ^ (r & 15)) & 15)) << 3;
    *(uint4*)&As[r * 256 + col] = *(const uint4*)(xcat + (mg * 64 + r) * 256 + v * 8);
    *(uint4*)&Bs[r * 256 + col] = *(const uint4*)(W1T + (ng * 64 + r) * 256 + v * 8);
  }
  __syncthreads();

  floatx4 acc[4];
#pragma unroll
  for (int mt = 0; mt < 4; ++mt) acc[mt] = (floatx4)0.f;

  const char* Ab = (const char*)As;
  const char* Bb = (const char*)Bs + wr * 16 * 512;
  const int base_sw = l15 * 512 + ((quad ^ l15) << 4);

#pragma unroll
  for (int ks = 0; ks < 8; ++ks) {
    const int swz = base_sw ^ (ks << 6);
    short8 bfr = *(const short8*)(Bb + swz);
#pragma unroll
    for (int mt = 0; mt < 4; ++mt) {
      short8 afr = *(const short8*)(Ab + mt * 8192 + swz);
      acc[mt] = __builtin_amdgcn_mfma_f32_16x16x32_bf16(afr, bfr, acc[mt], 0, 0, 0);
    }
  }

  const int ch = ng * 64 + wr * 16 + l15;          // 0..511 (wave-uniform side)
  const float bias = (ch < 256) ? b1[ch] : 0.f;
  unsigned short* dst = (ch < 256) ? PiH : PjH;
  const int chan = ch & 255;
#pragma unroll
  for (int mt = 0; mt < 4; ++mt)
#pragma unroll
    for (int r = 0; r < 4; ++r) {
      int row = mg * 64 + mt * 16 + quad * 4 + r;  // global row b*256+pos
      dst[row * 256 + chan] = f2h(acc[mt][r] + bias);
    }
}

// ---- k_main: packed items (R10) + fp8 pair-GEMM. Item = (i, jt); 1136/b,
// prefix P = {0,30,92,186,312,470,660,882}. Grid (142, 8b); 8 waves/block,
// zero skipped waves. A = relu_fp16(Pi+Pj) -> e4m3 (pack_fp8); B = W2 e4m3
// x16 in 32KB LDS (16B-granule XOR swizzle, 2-way bank alias = free).
// mfma_f32_16x16x32_fp8_fp8: same rate as fp16, HALF the LDS B-traffic.
// acc 64 AGPR + ~60 arch <= (512,4)'s 128-reg cap -> 4 waves/SIMD.
__global__ __launch_bounds__(512, 4) void k_main(
    const unsigned short* __restrict__ PiH, const unsigned short* __restrict__ PjH,
    const unsigned char* __restrict__ W2F8, const float* __restrict__ b2,
    const float* __restrict__ W3, const float* __restrict__ b3,
    float* __restrict__ outm) {
  const int b = blockIdx.y;
  const int tid = threadIdx.x;
  const int wr = tid >> 6;              // wave 0..7
  const int lane = tid & 63, quad = lane >> 4, l15 = lane & 15;

  __shared__ unsigned char W2s[128 * 256];   // 32KB fp8, [n][k'] swizzled

  // stage 32KB: 2048 16B chunks, 4/thread; colblk = v ^ (n&15)
#pragma unroll
  for (int it = 0; it < 4; ++it) {
    int e = it * 512 + tid;
    int n = e >> 4, v = e & 15;
    *(uint4*)&W2s[n * 256 + ((v ^ (n & 15)) << 4)] =
        *(const uint4*)(W2F8 + n * 256 + v * 16);
  }
  __syncthreads();

  // decode packed item e -> (jt, i)   [wave-uniform]
  const int e = blockIdx.x * 8 + wr;       // 0..1135
  int jt = 0, base = 0;
  if (e >= 30)  { jt = 1; base = 30;  }
  if (e >= 92)  { jt = 2; base = 92;  }
  if (e >= 186) { jt = 3; base = 186; }
  if (e >= 312) { jt = 4; base = 312; }
  if (e >= 470) { jt = 5; base = 470; }
  if (e >= 660) { jt = 6; base = 660; }
  if (e >= 882) { jt = 7; base = 882; }
  const int i = e - base;                  // 0 .. jt*32+29

  // B-frag addr: n*256 + (((ks*2 + (quad>>1)) ^ (n&15))<<4) + (quad&1)*8,
  // n = nt*16 + l15  ->  base ^ (ks<<5), + nt*4096 immediate.
  const char* W2base = (const char*)&W2s[0];
  const int base_sw = l15 * 256 + ((((quad >> 1) ^ l15) & 15) << 4) + ((quad & 1) << 3);
  const unsigned short* Pjb = PjH + ((b << 8) + jt * 32 + l15) * 256 + quad * 8;
  const unsigned short* PiRow = PiH + ((b << 8) + i) * 256 + quad * 8;

  floatx4 acc[2][8];
#pragma unroll
  for (int mt = 0; mt < 2; ++mt)
#pragma unroll
    for (int nt = 0; nt < 8; ++nt) acc[mt][nt] = (floatx4)0.f;

  union U4 { uint4 v; half8 h; };
  U4 piR[2], pjR[2][2];
  piR[0].v = *(const uint4*)(PiRow);
  pjR[0][0].v = *(const uint4*)(Pjb);
  pjR[0][1].v = *(const uint4*)(Pjb + 4096);   // mt=1: +16 rows

#pragma unroll
  for (int ks = 0; ks < 8; ++ks) {
    const int cur = ks & 1, nxt = cur ^ 1;
    if (ks < 7) {                    // depth-1 global prefetch
      piR[nxt].v = *(const uint4*)(PiRow + (ks + 1) * 32);
      pjR[nxt][0].v = *(const uint4*)(Pjb + (ks + 1) * 32);
      pjR[nxt][1].v = *(const uint4*)(Pjb + 4096 + (ks + 1) * 32);
    }
    // build A-frags: packed fp16 relu(Pi+Pj), then pack to e4m3
    const half8 s0 = __builtin_elementwise_max(piR[cur].h + pjR[cur][0].h,
                                               (half8)(_Float16)0);
    const half8 s1 = __builtin_elementwise_max(piR[cur].h + pjR[cur][1].h,
                                               (half8)(_Float16)0);
    const long a0 = pack_fp8(s0);
    const long a1 = pack_fp8(s1);
    const char* baddr = W2base + (base_sw ^ (ks << 5));
#pragma unroll
    for (int nt = 0; nt < 8; ++nt) {
      long bfr = *(const long*)(baddr + nt * 4096);
      acc[0][nt] = __builtin_amdgcn_mfma_f32_16x16x32_fp8_fp8(a0, bfr, acc[0][nt], 0, 0, 0);
      acc[1][nt] = __builtin_amdgcn_mfma_f32_16x16x32_fp8_fp8(a1, bfr, acc[1][nt], 0, 0, 0);
    }
  }

  // epilogue: score[j] = tanh(sum_n W3[n]*relu(C[j,n]/16 + b2[n]) + b3)
  float* orow = outm + ((b << 8) + i) * 256 + jt * 32;
  const float b3v = b3[0];
  const float s16 = 0.0625f;               // undo W2 x16 scale
#pragma unroll
  for (int mt = 0; mt < 2; ++mt) {
    float p0 = 0, p1 = 0, p2 = 0, p3 = 0;
#pragma unroll
    for (int nt = 0; nt < 8; ++nt) {
      float w3v = W3[nt * 16 + l15];
      float b2v = b2[nt * 16 + l15];
      floatx4 a = acc[mt][nt];
      p0 += fmaxf(fmaf(a[0], s16, b2v), 0.f) * w3v;
      p1 += fmaxf(fmaf(a[1], s16, b2v), 0.f) * w3v;
      p2 += fmaxf(fmaf(a[2], s16, b2v), 0.f) * w3v;
      p3 += fmaxf(fmaf(a[3], s16, b2v), 0.f) * w3v;
    }
#pragma unroll
    for (int m = 8; m >= 1; m >>= 1) {   // reduce over the 16 n-cols per quad
      p0 += __shfl_xor(p0, m, 16);
      p1 += __shfl_xor(p1, m, 16);
      p2 += __shfl_xor(p2, m, 16);
      p3 += __shfl_xor(p3, m, 16);
    }
    if (l15 == 0) {
      const int jl = jt * 32 + mt * 16 + quad * 4;   // global j of reg 0
      float ps[4] = {p0, p1, p2, p3};
#pragma unroll
      for (int r = 0; r < 4; ++r) {
        int j = jl + r;
        float s = fast_tanh(ps[r] + b3v);
        bool valid = (j >= i + 2) && (j - i != 255);
        orow[mt * 16 + quad * 4 + r] = valid ? s : 0.f;
      }
    }
  }
}

extern "C" void kernel_launch(void* const* d_in, const int* in_sizes, int n_in,
                              void* d_out, int out_size, void* d_ws, size_t ws_size,
                              hipStream_t stream) {
  const float* x  = (const float*)d_in[0];   // [8,256,128]
  const float* W1 = (const float*)d_in[1];   // [512,256]
  const float* b1 = (const float*)d_in[2];   // [256]
  const float* W2 = (const float*)d_in[3];   // [256,128]
  const float* b2 = (const float*)d_in[4];   // [128]
  const float* W3 = (const float*)d_in[5];   // [128]
  const float* b3 = (const float*)d_in[6];   // [1]
  float* out = (float*)d_out;

  // ws (ushort units): PiH 524288 | PjH 524288 | W1T 131072 | xcat 524288 | W2F8 32KB
  unsigned short* PiH  = (unsigned short*)d_ws;
  unsigned short* PjH  = PiH + 524288;
  unsigned short* W1T  = PjH + 524288;
  unsigned short* xcat = W1T + 131072;
  unsigned char*  W2F8 = (unsigned char*)(xcat + 524288);

  k_prep<<<4680, 256, 0, stream>>>(x, W1, W2, out, W2F8, W1T, xcat);
  k_proj<<<256, 256, 0, stream>>>(xcat, W1T, b1, PiH, PjH);
  dim3 grid_main(142, 8);
  k_main<<<grid_main, 512, 0, stream>>>(PiH, PjH, W2F8, b2, W3, b3, out + 2048);
}